// Round 7
// baseline (1958.803 us; speedup 1.0000x reference)
//
#include <hip/hip_runtime.h>

// Batched Hungarian matcher — TRAJECTORY-EXACT Jonker-Volgenant replication
// of the numpy reference (zero initial duals, rows in order, f64 on exact
// f32 costs, lowest-index tie-breaks). R6 post-mortem: the optimum is NOT
// unique (L1-metric degeneracy: a_j terms cancel and |.| re-associates for
// non-interleaved quadruples), so the reference's trajectory must be
// replicated, not just "an" optimum.
//
// R7 structure: single-wave solve (NO barriers per pop) + exact-gated
// candidate pruning + single-wave full-scan fallback.
//  - setup (8 waves): per row i an EXACT candidate set {j: cf(i,j) < th_i}
//    (largest of 6 tiers with count <= 40), entries {cf,j} pre-packed.
//  - per pop: stateless flat scan of records x candidates (1 entry/lane,
//    one 8B load + one v32 load, no chases), in-wave butterfly (m1,j,m2).
//  - exactness: certify unique true argmin (m2-m1 > 2*Dmax), resolve j* in
//    exact f64 numpy-order over ALL scanned-row records (incl. omissions),
//    accept only if value < LB = min_s((minv_s + th_s) - u_s) (valid:
//    v<=0, fp rounding monotone). Else undo + full-scan rerun of the row.
// Duals u,v and all pop values exact f64 == numpy.

#define Bb 32
#define Nn 4096
#define Mm 128
#define Tt 512
#define CND 40         // max candidates per row
#define RECMAX 136
#define PRUNECAP 56
#define NTIER 6

__global__ __launch_bounds__(Tt, 1)
void hungarian_kernel(const float* __restrict__ predict_scores,
                      const float* __restrict__ predict_points,
                      const int*   __restrict__ scores,
                      const float* __restrict__ points,
                      int* __restrict__ out)
{
    __shared__ double vvl[Nn];            // column duals (exact f64)
    __shared__ float  v32[Nn];            // f32 mirror; -1e30 = popped poison
    __shared__ float  pn1l[Nn];           // -softmax prob class1 (exact f32)
    __shared__ float2 qxl[Nn];            // prediction points
    __shared__ float2 cand[Mm * CND];     // {cf, j_bits} per row candidate
    __shared__ unsigned char path_lds[Nn];
    __shared__ signed char   row4col[Nn]; // matched row per col (-1 free)
    __shared__ double uu[Mm];
    __shared__ short  col4row[Mm];
    __shared__ double srow_val[Mm];
    __shared__ unsigned char SRr[Mm];
    __shared__ float  tx0[Mm], tx1[Mm];
    __shared__ unsigned char tch1[Mm];    // 1 if class==1
    __shared__ float  theta_sh[Mm];
    __shared__ short  cc_sh[Mm];
    __shared__ double rec_minv[RECMAX], rec_u[RECMAX];
    __shared__ float  rec_t0[RECMAX], rec_t1[RECMAX], rec_b32[RECMAX];
    __shared__ short  rec_row[RECMAX], rec_cc[RECMAX];
    __shared__ int    rec_cb[RECMAX];
    __shared__ unsigned char rec_ch1[RECMAX];
    __shared__ short  pcol[RECMAX];
    __shared__ double pval[RECMAX];

    const int tid = threadIdx.x;
    const int b   = blockIdx.x;
    const double INFD = __builtin_inf();
    const float  INFF = __builtin_inff();
    const float* ps = predict_scores + (size_t)b * Nn * 2;
    const float* pp = predict_points + (size_t)b * Nn * 2;

    // ================= phase 0: column data =================
    for (int k = 0; k < Nn / Tt; ++k) {
        int j = tid + k * Tt;
        float2 sc = ((const float2*)ps)[j];
        float mx = fmaxf(sc.x, sc.y);
        float e0 = expf(sc.x - mx), e1 = expf(sc.y - mx);
        float sm = e0 + e1;
        pn1l[j] = -(e1 / sm);
        qxl[j]  = ((const float2*)pp)[j];
        vvl[j] = 0.0; v32[j] = 0.0f;
        row4col[j] = -1;
    }
    if (tid < Mm) {
        uu[tid] = 0.0; col4row[tid] = -1; SRr[tid] = 0;
        tx0[tid] = points[(size_t)b * Mm * 2 + 2 * tid];
        tx1[tid] = points[(size_t)b * Mm * 2 + 2 * tid + 1];
        tch1[tid] = (scores[(size_t)b * Mm + tid] == 1) ? 1 : 0;
    }
    __syncthreads();

    // ================= candidate build (8 waves x 16 rows) =================
    {
        const int wv = tid >> 6, lane = tid & 63;
        const float dlt[NTIER] = {0.4f, 0.22f, 0.12f, 0.065f, 0.035f, 0.02f};
        for (int rr = 0; rr < Mm / 8; ++rr) {
            int i = wv * (Mm / 8) + rr;
            float t0 = tx0[i], t1 = tx1[i];
            bool ch1 = tch1[i];
            float cfreg[64];
            float m = INFF;
            #pragma unroll
            for (int k = 0; k < 64; ++k) {
                int j = (k << 6) + lane;
                float pres;
                if (ch1) pres = pn1l[j];
                else {
                    float2 sc = ((const float2*)ps)[j];
                    float mx = fmaxf(sc.x, sc.y);
                    float e0 = expf(sc.x - mx), e1 = expf(sc.y - mx);
                    pres = -(e0 / (e0 + e1));
                }
                float2 qp = qxl[j];
                float cf = pres + (fabsf(qp.x - t0) + fabsf(qp.y - t1));
                cfreg[k] = cf;
                m = fminf(m, cf);
            }
            #pragma unroll
            for (int off = 32; off > 0; off >>= 1) m = fminf(m, __shfl_xor(m, off));
            int cnt[NTIER];
            #pragma unroll
            for (int t = 0; t < NTIER; ++t) cnt[t] = 0;
            #pragma unroll
            for (int k = 0; k < 64; ++k) {
                float c = cfreg[k];
                #pragma unroll
                for (int t = 0; t < NTIER; ++t) cnt[t] += (c < m + dlt[t]) ? 1 : 0;
            }
            #pragma unroll
            for (int t = 0; t < NTIER; ++t) {
                #pragma unroll
                for (int off = 32; off > 0; off >>= 1) cnt[t] += __shfl_xor(cnt[t], off);
            }
            float th = -INFF; int have = 0;
            #pragma unroll
            for (int t = 0; t < NTIER; ++t)
                if (!have && cnt[t] <= CND) { th = m + dlt[t]; have = 1; }
            int base = 0;
            #pragma unroll
            for (int k = 0; k < 64; ++k) {
                bool pred = cfreg[k] < th;
                unsigned long long mask = __ballot(pred);
                if (pred) {
                    int idx = base + (int)__popcll(mask & ((1ull << lane) - 1ull));
                    int j = (k << 6) + lane;
                    cand[i * CND + idx] = make_float2(cfreg[k], __uint_as_float((unsigned)j));
                }
                base += (int)__popcll(mask);
            }
            if (lane == 0) { theta_sh[i] = th; cc_sh[i] = (short)base; }
        }
    }
    __syncthreads();
    if (tid >= 64) return;     // waves 1..7 done; wave 0 solves (no barriers)

    // ================= wave-0 JV solve =================
    float Vcap = 0.0f, Umax = 0.0f;
    bool anyCh0g = false;

    for (int cur_row = 0; cur_row < Mm; ++cur_row) {
        float shrF[64];
        int SpopPrev = 0;
        int sink = -1;
        double minvF = 0.0;

        for (int attempt = 0; attempt < 2; ++attempt) {
            if (attempt == 1) {
                // undo pruned attempt: restore v32, clear SRr
                for (int e = tid; e < SpopPrev; e += 64) {
                    int c = pcol[e];
                    v32[c] = (float)vvl[c];
                    int r = (int)row4col[c];
                    if (r >= 0) SRr[r] = 0;
                }
                #pragma unroll
                for (int k = 0; k < 64; ++k) shrF[k] = INFF;
            }
            int Srow = 0, Spop = 0;
            double minv = 0.0, LB = INFD;
            float Dmax = 0.0f;
            double curU; float curT0, curT1, curB32; bool curCh1;
            // ---- append(cur_row, 0.0) ----
            {
                int r = cur_row;
                double ur = uu[r];
                float th = theta_sh[r];
                LB = fmin(LB, (0.0 + (double)th) - ur);
                Umax = fmaxf(Umax, fabsf((float)ur));
                curU = ur; curT0 = tx0[r]; curT1 = tx1[r];
                curCh1 = tch1[r]; anyCh0g |= !curCh1;
                curB32 = (float)(0.0 - ur);
                if (tid == 0) {
                    rec_minv[0] = 0.0; rec_u[0] = ur;
                    rec_t0[0] = curT0; rec_t1[0] = curT1;
                    rec_b32[0] = curB32;
                    rec_row[0] = (short)r; rec_cc[0] = cc_sh[r];
                    rec_cb[0] = r * CND; rec_ch1[0] = curCh1 ? 1 : 0;
                }
                Srow = 1;
            }
            bool fail = false;

            for (int pops = 0; pops < RECMAX - 4; ++pops) {
                float dlt = 3e-6f * (4.0f + fabsf((float)minv) + Umax + Vcap);
                Dmax = fmaxf(Dmax, dlt);
                float m1 = INFF, m2 = INFF; int j1 = Nn;

                if (attempt == 0) {
                    if (Srow > PRUNECAP) { fail = true; break; }
                    // ---- pruned stateless scan: records x candidates ----
                    for (int s = 0; s < Srow; ++s) {
                        int   cb  = rec_cb[s];
                        int   ccs = rec_cc[s];
                        float b32 = rec_b32[s];
                        float val = INFF; int jj = Nn;
                        if (tid < ccs) {
                            float2 e = cand[cb + tid];
                            int j = (int)__float_as_uint(e.y);
                            val = (b32 + e.x) - v32[j];
                            jj = j;
                        }
                        bool lt = val < m1;
                        m2 = fminf(m2, lt ? m1 : val);
                        m1 = lt ? val : m1;
                        j1 = lt ? jj : j1;
                    }
                } else {
                    // ---- fallback full scan (running f32 shortest) ----
                    #pragma unroll
                    for (int k = 0; k < 64; ++k) {
                        int j = (k << 6) + tid;
                        float pres;
                        if (curCh1) pres = pn1l[j];
                        else {
                            float2 sc = ((const float2*)ps)[j];
                            float mx = fmaxf(sc.x, sc.y);
                            float e0 = expf(sc.x - mx), e1 = expf(sc.y - mx);
                            pres = -(e0 / (e0 + e1));
                        }
                        float2 qp = qxl[j];
                        float cf = pres + (fabsf(qp.x - curT0) + fabsf(qp.y - curT1));
                        float r = (curB32 + cf) - v32[j];
                        float sF = fminf(shrF[k], r);
                        shrF[k] = sF;
                        bool lt = sF < m1;
                        m2 = fminf(m2, lt ? m1 : sF);
                        m1 = lt ? sF : m1;
                        j1 = lt ? j : j1;
                    }
                }
                // ---- in-wave butterfly (m1, j1, m2) ----
                #pragma unroll
                for (int off = 32; off > 0; off >>= 1) {
                    float o1 = __shfl_xor(m1, off);
                    int   oj = __shfl_xor(j1, off);
                    float o2 = __shfl_xor(m2, off);
                    m2 = fminf(fminf(m2, o2), fmaxf(m1, o1));
                    bool take = o1 < m1;
                    m1 = take ? o1 : m1;
                    j1 = take ? oj : j1;
                }
                const bool cert = (m2 - m1) > (2.0f * Dmax);
                int jstar, pr; double sv;
                if (cert) {
                    jstar = j1;
                    // ---- exact resolve over ALL records (all lanes) ----
                    double vj = vvl[jstar];
                    float p1v = pn1l[jstar];
                    float p0v = 0.0f;
                    if (anyCh0g) {
                        float2 sc = ((const float2*)ps)[jstar];
                        float mx = fmaxf(sc.x, sc.y);
                        float e0 = expf(sc.x - mx), e1 = expf(sc.y - mx);
                        p0v = -(e0 / (e0 + e1));
                    }
                    float2 qp = qxl[jstar];
                    sv = INFD; pr = -1;
                    for (int s = 0; s < Srow; ++s) {
                        float pres = rec_ch1[s] ? p1v : p0v;
                        float cf = pres + (fabsf(qp.x - rec_t0[s]) + fabsf(qp.y - rec_t1[s]));
                        double r = ((rec_minv[s] + (double)cf) - rec_u[s]) - vj;
                        if (r < sv) { sv = r; pr = (int)rec_row[s]; }
                    }
                    if (attempt == 0 && !(sv < LB)) { fail = true; break; }
                } else {
                    if (attempt == 0) { fail = true; break; }
                    // ---- fallback uncertified: exact multi-contender ----
                    float thr = m1 + 2.0f * Dmax;
                    double bv = INFD; int bj = Nn, bp = -1;
                    #pragma unroll
                    for (int k = 0; k < 64; ++k) {
                        if (shrF[k] <= thr) {
                            int j = (k << 6) + tid;
                            double vj = vvl[j];
                            float p1v = pn1l[j];
                            float p0v = 0.0f;
                            if (anyCh0g) {
                                float2 sc = ((const float2*)ps)[j];
                                float mx = fmaxf(sc.x, sc.y);
                                float e0 = expf(sc.x - mx), e1 = expf(sc.y - mx);
                                p0v = -(e0 / (e0 + e1));
                            }
                            float2 qp = qxl[j];
                            double sv2 = INFD; int pr2 = -1;
                            for (int s = 0; s < Srow; ++s) {
                                float pres = rec_ch1[s] ? p1v : p0v;
                                float cf = pres + (fabsf(qp.x - rec_t0[s]) + fabsf(qp.y - rec_t1[s]));
                                double r = ((rec_minv[s] + (double)cf) - rec_u[s]) - vj;
                                if (r < sv2) { sv2 = r; pr2 = (int)rec_row[s]; }
                            }
                            if (sv2 < bv) { bv = sv2; bj = j; bp = pr2; }
                        }
                    }
                    #pragma unroll
                    for (int off = 32; off > 0; off >>= 1) {
                        double ov = __shfl_xor(bv, off);
                        int    oj = __shfl_xor(bj, off);
                        int    op = __shfl_xor(bp, off);
                        if (ov < bv || (ov == bv && oj < bj)) { bv = ov; bj = oj; bp = op; }
                    }
                    jstar = bj; sv = bv; pr = bp;
                }
                // ---- commit pop ----
                minv = sv;
                int r4 = (int)row4col[jstar];
                if (tid == 0) {
                    path_lds[jstar] = (unsigned char)pr;
                    pcol[Spop] = (short)jstar; pval[Spop] = sv;
                    v32[jstar] = -1e30f;               // exclude from scans
                }
                if (attempt == 1) {
                    int slot = jstar >> 6;
                    if (tid == (jstar & 63)) {
                        #pragma unroll
                        for (int k = 0; k < 64; ++k)
                            if (k == slot) shrF[k] = INFF;
                    }
                }
                Spop++;
                if (r4 < 0) { sink = jstar; break; }
                if (tid == 0) { SRr[r4] = 1; srow_val[r4] = sv; }
                // ---- append(r4, sv) ----
                {
                    double ur = uu[r4];
                    float th = theta_sh[r4];
                    LB = fmin(LB, (sv + (double)th) - ur);
                    Umax = fmaxf(Umax, fabsf((float)ur));
                    curU = ur; curT0 = tx0[r4]; curT1 = tx1[r4];
                    curCh1 = tch1[r4]; anyCh0g |= !curCh1;
                    curB32 = (float)(sv - ur);
                    if (tid == 0) {
                        rec_minv[Srow] = sv; rec_u[Srow] = ur;
                        rec_t0[Srow] = curT0; rec_t1[Srow] = curT1;
                        rec_b32[Srow] = curB32;
                        rec_row[Srow] = (short)r4; rec_cc[Srow] = cc_sh[r4];
                        rec_cb[Srow] = r4 * CND; rec_ch1[Srow] = curCh1 ? 1 : 0;
                    }
                    Srow++;
                }
            }
            if (sink >= 0) { minvF = minv; break; }
            SpopPrev = Spop;
            (void)fail;
        }

        // ---- row end: exact dual updates + augment (no barriers) ----
        int SpopF = 0;
        {
            // Spop of the successful attempt equals number of pops; recover
            // count: pops recorded in pcol up to sink; sink is last entry.
            // We tracked it implicitly: walk pval until... simpler: recompute
            // from pcol? We know the final attempt's Spop via pval[0] usage
            // only; store count in a register: done below via loop variable.
        }
        // NOTE: Spop of successful attempt is carried via shared pcol/pval
        // and the register 'SpopPrev' trick is avoided by recomputing inside
        // the attempt loop; we saved it here:
        // (we rely on the fact that the successful attempt's Spop was the
        //  last value of the local variable; easiest: re-scan for sink)
        for (int e = 0; e < RECMAX; ++e) {
            if ((int)pcol[e] == sink) { SpopF = e + 1; break; }
        }
        for (int r = tid; r < Mm; r += 64) {
            if (r == cur_row) uu[r] += minvF;
            else if (SRr[r]) { uu[r] += minvF - srow_val[r]; SRr[r] = 0; }
        }
        for (int e = tid; e < SpopF; e += 64) {
            int c = pcol[e];
            double nv = vvl[c] - (minvF - pval[e]);
            vvl[c] = nv;
            v32[c] = (float)nv;
        }
        Vcap += (float)(minvF - pval[0]) + 1e-6f;
        if (tid == 0) {
            int j = sink;
            for (;;) {
                int i2 = (int)path_lds[j];
                row4col[j] = (signed char)i2;
                int nxt = (int)col4row[i2];
                col4row[i2] = (short)j;
                j = nxt;
                if (i2 == cur_row) break;
            }
        }
    }

    // ================= emit =================
    for (int r = tid; r < Mm; r += 64) {
        int myj = (int)col4row[r];
        int rank = 0;
        for (int t = 0; t < Mm; ++t) rank += ((int)col4row[t] < myj) ? 1 : 0;
        out[b * Mm + r] = b;
        out[Bb * Mm + b * Mm + rank] = myj;
        out[2 * Bb * Mm + b * Mm + rank] = r;
    }
}

extern "C" void kernel_launch(void* const* d_in, const int* in_sizes, int n_in,
                              void* d_out, int out_size, void* d_ws, size_t ws_size,
                              hipStream_t stream) {
    (void)in_sizes; (void)n_in; (void)d_ws; (void)ws_size; (void)out_size;
    const float* predict_scores = (const float*)d_in[0];
    const float* predict_points = (const float*)d_in[1];
    const int*   scores         = (const int*)d_in[2];
    const float* points         = (const float*)d_in[3];
    int* out = (int*)d_out;
    hipLaunchKernelGGL(hungarian_kernel, dim3(Bb), dim3(64 * 8), 0, stream,
                       predict_scores, predict_points, scores, points, out);
}

// Round 8
// 669.644 us; speedup vs baseline: 2.9251x; 2.9251x over previous
//
#include <hip/hip_runtime.h>

// Batched Hungarian matcher — TRAJECTORY-EXACT Jonker-Volgenant replication
// of the numpy reference (zero initial duals, rows in order, exact f64 on
// exact f32 costs, lowest-index tie-breaks everywhere).
//
// R8: single-wave solve, zero barriers per pop.
//  - pruned pop: stateless scan over (scanned-row records) x (per-row exact
//    candidate sets, cf < theta_i, |C_i| <= 64, one cand/lane) computed
//    DIRECTLY in f64 => exact values, no certification needed. In-wave
//    lex-(val,j) butterfly. Accept pop iff val < LB where
//    LB = min_s fl64(fl64(minv_s + theta_s) - u_s): since v_j <= 0 and
//    round-to-nearest is monotone, every omitted (row,col) relax >= LB, so
//    an accepted pop (value, index, predecessor) == numpy's.
//  - predecessor: redundant exact re-scan of records for j* (first strict
//    improver in scan order == numpy path semantics).
//  - fallback (gate fails): single-wave full scan, f32 running shortest in
//    STATIC-indexed registers + popped-bitmask (NO dynamic reg indexing —
//    R7's scratch-spill bug), certified unique argmin via (m2-m1 > 2*Dmax)
//    else exact multi-contender resolve (R5-proven logic).
// Duals u,v and all pop values exact f64 == numpy.

#define Bb 32
#define Nn 4096
#define Mm 128
#define CAP 64
#define RECMAX 136

__global__ __launch_bounds__(512, 1)
void hungarian_kernel(const float* __restrict__ predict_scores,
                      const float* __restrict__ predict_points,
                      const int*   __restrict__ scores,
                      const float* __restrict__ points,
                      int* __restrict__ out)
{
    __shared__ double vvl[Nn];            // column duals (exact f64); -inf = popped
    __shared__ float  pn1l[Nn];           // -softmax prob class1 (exact f32)
    __shared__ float2 qxl[Nn];            // prediction points
    __shared__ float  cand_cf[Mm * CAP];  // candidate costs per row
    __shared__ unsigned short cand_jj[Mm * CAP]; // candidate column ids
    __shared__ unsigned char path_lds[Nn];
    __shared__ signed char   row4col_s[Nn];      // matched row per col (-1 free)
    __shared__ double uu[Mm];
    __shared__ short  col4row[Mm];
    __shared__ float  tx0[Mm], tx1[Mm];
    __shared__ unsigned char tch1[Mm];
    __shared__ float  theta_s[Mm];
    __shared__ short  ccnt[Mm];
    __shared__ double rec_minv[RECMAX], rec_u[RECMAX];
    __shared__ float  rec_t0[RECMAX], rec_t1[RECMAX];
    __shared__ short  rec_row[RECMAX], rec_cc[RECMAX];
    __shared__ unsigned char rec_ch1[RECMAX];
    __shared__ short  pcol[RECMAX];
    __shared__ double pval[RECMAX], pvold[RECMAX];

    const int tid = threadIdx.x;
    const int b   = blockIdx.x;
    const double INFD = __builtin_inf();
    const float  INFF = __builtin_inff();
    const float* ps = predict_scores + (size_t)b * Nn * 2;
    const float* pp = predict_points + (size_t)b * Nn * 2;

    // ---------------- setup ----------------
    for (int k = 0; k < Nn / 512; ++k) {
        int j = tid + k * 512;
        float2 sc = ((const float2*)ps)[j];
        float mx = fmaxf(sc.x, sc.y);
        float e0 = expf(sc.x - mx), e1 = expf(sc.y - mx);
        float sm = e0 + e1;
        pn1l[j] = -(e1 / sm);
        qxl[j]  = ((const float2*)pp)[j];
        vvl[j] = 0.0;
        row4col_s[j] = -1;
    }
    if (tid < Mm) {
        uu[tid] = 0.0;
        col4row[tid] = -1;
        tx0[tid] = points[(size_t)b * Mm * 2 + 2 * tid];
        tx1[tid] = points[(size_t)b * Mm * 2 + 2 * tid + 1];
        tch1[tid] = (scores[(size_t)b * Mm + tid] == 1) ? 1 : 0;
    }
    __syncthreads();

    // ---------------- candidate build (8 waves x 16 rows) ----------------
    {
        const int wv = tid >> 6, lane = tid & 63;
        for (int rr = 0; rr < Mm / 8; ++rr) {
            int i = wv * (Mm / 8) + rr;
            float t0 = tx0[i], t1 = tx1[i];
            bool ch1 = tch1[i] != 0;
            float cfreg[64];                 // static-indexed only
            float m = INFF;
            #pragma unroll
            for (int k = 0; k < 64; ++k) {
                int j = (k << 6) | lane;
                float pres;
                if (ch1) pres = pn1l[j];
                else {
                    float2 sc = ((const float2*)ps)[j];
                    float mx = fmaxf(sc.x, sc.y);
                    float e0 = expf(sc.x - mx), e1 = expf(sc.y - mx);
                    pres = -(e0 / (e0 + e1));
                }
                float2 qp = qxl[j];
                float cf = pres + (fabsf(qp.x - t0) + fabsf(qp.y - t1));
                cfreg[k] = cf;
                m = fminf(m, cf);
            }
            #pragma unroll
            for (int off = 32; off > 0; off >>= 1) m = fminf(m, __shfl_xor(m, off));
            float thv[6] = {m + 0.512f, m + 0.256f, m + 0.128f,
                            m + 0.064f, m + 0.032f, m + 0.016f};
            int cnt[6] = {0, 0, 0, 0, 0, 0};
            #pragma unroll
            for (int k = 0; k < 64; ++k) {
                float c = cfreg[k];
                #pragma unroll
                for (int t = 0; t < 6; ++t) cnt[t] += (c < thv[t]) ? 1 : 0;
            }
            #pragma unroll
            for (int t = 0; t < 6; ++t) {
                #pragma unroll
                for (int off = 32; off > 0; off >>= 1) cnt[t] += __shfl_xor(cnt[t], off);
            }
            float th = 0.0f; int have = 0;
            #pragma unroll
            for (int t = 0; t < 6; ++t)
                if (!have && cnt[t] <= CAP) { th = thv[t]; have = 1; }
            int base = 0;
            if (have) {
                #pragma unroll
                for (int k = 0; k < 64; ++k) {
                    bool p = cfreg[k] < th;
                    unsigned long long mk = __ballot(p);
                    if (p) {
                        int idx = base + (int)__popcll(mk & ((1ull << lane) - 1ull));
                        cand_cf[i * CAP + idx] = cfreg[k];
                        cand_jj[i * CAP + idx] = (unsigned short)((k << 6) | lane);
                    }
                    base += (int)__popcll(mk);
                }
            }
            if (lane == 0) {
                theta_s[i] = have ? th : -INFF;
                ccnt[i] = (short)(have ? base : 0);
            }
        }
    }
    __syncthreads();
    if (tid >= 64) return;       // wave 0 solves alone; no barriers below

    const int lane = tid;
    float Vcap = 0.0f, Umax = 0.0f;

    for (int cur_row = 0; cur_row < Mm; ++cur_row) {
        int Srow = 0, Spop = 0, sink = -1;
        double minv = 0.0;
        bool fail = false, anyCh0 = false;

        // ============ attempt 0: pruned (exact f64, LB-gated) ============
        {
            double LB = INFD;
            {   // append cur_row record
                int r = cur_row;
                double ur = uu[r];
                LB = fmin(LB, ((0.0 + (double)theta_s[r]) - ur));
                Umax = fmaxf(Umax, fabsf((float)ur));
                bool c1 = tch1[r] != 0;
                anyCh0 = !c1;
                if (lane == 0) {
                    rec_minv[0] = 0.0; rec_u[0] = ur;
                    rec_t0[0] = tx0[r]; rec_t1[0] = tx1[r];
                    rec_row[0] = (short)r; rec_cc[0] = ccnt[r];
                    rec_ch1[0] = c1 ? 1 : 0;
                }
                Srow = 1;
            }
            for (int pops = 0; pops < RECMAX - 4; ++pops) {
                // ---- stateless exact scan: records x candidates ----
                double m = INFD; int mj = Nn;
                for (int s = 0; s < Srow; ++s) {
                    int rb = (int)rec_row[s] * CAP;
                    int cs = (int)rec_cc[s];
                    double pm = rec_minv[s], pu = rec_u[s];
                    if (lane < cs) {
                        float cf = cand_cf[rb + lane];
                        int j = (int)cand_jj[rb + lane];
                        double val = ((pm + (double)cf) - pu) - vvl[j]; // +inf if popped
                        if (val < m || (val == m && j < mj)) { m = val; mj = j; }
                    }
                }
                #pragma unroll
                for (int off = 32; off > 0; off >>= 1) {
                    double om = __shfl_xor(m, off);
                    int    oj = __shfl_xor(mj, off);
                    if (om < m || (om == m && oj < mj)) { m = om; mj = oj; }
                }
                if (!(m < LB)) { fail = true; break; }     // exactness gate
                // ---- exact predecessor resolve (all lanes, redundant) ----
                double vj = vvl[mj];
                float p1 = pn1l[mj], p0 = 0.0f;
                if (anyCh0) {
                    float2 sc = ((const float2*)ps)[mj];
                    float mx = fmaxf(sc.x, sc.y);
                    float e0 = expf(sc.x - mx), e1 = expf(sc.y - mx);
                    p0 = -(e0 / (e0 + e1));
                }
                float2 qp = qxl[mj];
                double best = INFD; int pred = -1;
                for (int s = 0; s < Srow; ++s) {
                    float pres = rec_ch1[s] ? p1 : p0;
                    float cfr = pres + (fabsf(qp.x - rec_t0[s]) + fabsf(qp.y - rec_t1[s]));
                    double r = ((rec_minv[s] + (double)cfr) - rec_u[s]) - vj;
                    if (r < best) { best = r; pred = (int)rec_row[s]; }
                }
                minv = best;                               // == m (gate-guaranteed)
                if (lane == 0) {
                    path_lds[mj] = (unsigned char)pred;
                    pcol[Spop] = (short)mj; pval[Spop] = best; pvold[Spop] = vj;
                    vvl[mj] = -INFD;                       // poison
                }
                Spop++;
                int r4 = (int)row4col_s[mj];
                if (r4 < 0) { sink = mj; break; }
                double ur = uu[r4];
                LB = fmin(LB, ((best + (double)theta_s[r4]) - ur));
                Umax = fmaxf(Umax, fabsf((float)ur));
                bool c1 = tch1[r4] != 0;
                anyCh0 = anyCh0 || !c1;
                if (lane == 0) {
                    rec_minv[Srow] = best; rec_u[Srow] = ur;
                    rec_t0[Srow] = tx0[r4]; rec_t1[Srow] = tx1[r4];
                    rec_row[Srow] = (short)r4; rec_cc[Srow] = ccnt[r4];
                    rec_ch1[Srow] = c1 ? 1 : 0;
                }
                Srow++;
            }
            if (sink < 0) fail = true;
        }

        // ============ attempt 1: full-scan fallback (spill-free) ============
        if (fail) {
            for (int e = lane; e < Spop; e += 64) vvl[(int)pcol[e]] = pvold[e]; // undo
            Srow = 0; Spop = 0; sink = -1; minv = 0.0;
            float Dmax = 0.0f;
            unsigned long long popped = 0ull;              // exclusion bitmask
            float shrF[64];                                // static-indexed ONLY
            #pragma unroll
            for (int k = 0; k < 64; ++k) shrF[k] = INFF;
            int ri = cur_row;
            double ur = uu[ri];
            float rt0 = tx0[ri], rt1 = tx1[ri];
            bool rch1 = tch1[ri] != 0;
            anyCh0 = !rch1;
            Umax = fmaxf(Umax, fabsf((float)ur));
            if (lane == 0) {
                rec_minv[0] = 0.0; rec_u[0] = ur;
                rec_t0[0] = rt0; rec_t1[0] = rt1;
                rec_row[0] = (short)ri; rec_cc[0] = 0;
                rec_ch1[0] = rch1 ? 1 : 0;
            }
            Srow = 1;
            for (int pops = 0; pops < RECMAX - 4; ++pops) {
                float dlt = 3e-6f * (4.0f + fabsf((float)minv) + Umax + Vcap);
                Dmax = fmaxf(Dmax, dlt);
                float rB32 = (float)(minv - ur);
                float m1 = INFF, m2 = INFF; int j1 = Nn;
                if (rch1) {
                    #pragma unroll
                    for (int k = 0; k < 64; ++k) {
                        int j = (k << 6) | lane;
                        float2 qp = qxl[j];
                        float cf = pn1l[j] + (fabsf(qp.x - rt0) + fabsf(qp.y - rt1));
                        float r = (rB32 + cf) - (float)vvl[j];   // +inf if popped
                        float sF = fminf(shrF[k], r);
                        shrF[k] = sF;
                        float sv = ((popped >> k) & 1ull) ? INFF : sF;
                        bool lt = (sv < m1) || (sv == m1 && j < j1);
                        m2 = fminf(m2, lt ? m1 : sv);
                        if (lt) { m1 = sv; j1 = j; }
                    }
                } else {
                    #pragma unroll
                    for (int k = 0; k < 64; ++k) {
                        int j = (k << 6) | lane;
                        float2 sc = ((const float2*)ps)[j];
                        float mx = fmaxf(sc.x, sc.y);
                        float e0 = expf(sc.x - mx), e1 = expf(sc.y - mx);
                        float pres = -(e0 / (e0 + e1));
                        float2 qp = qxl[j];
                        float cf = pres + (fabsf(qp.x - rt0) + fabsf(qp.y - rt1));
                        float r = (rB32 + cf) - (float)vvl[j];
                        float sF = fminf(shrF[k], r);
                        shrF[k] = sF;
                        float sv = ((popped >> k) & 1ull) ? INFF : sF;
                        bool lt = (sv < m1) || (sv == m1 && j < j1);
                        m2 = fminf(m2, lt ? m1 : sv);
                        if (lt) { m1 = sv; j1 = j; }
                    }
                }
                #pragma unroll
                for (int off = 32; off > 0; off >>= 1) {
                    float o1 = __shfl_xor(m1, off);
                    int   oj = __shfl_xor(j1, off);
                    float o2 = __shfl_xor(m2, off);
                    m2 = fminf(fminf(m2, o2), fmaxf(m1, o1));
                    bool take = (o1 < m1) || (o1 == m1 && oj < j1);
                    if (take) { m1 = o1; j1 = oj; }
                }
                int jstar, pred; double sv;
                if ((m2 - m1) > 2.0f * Dmax) {
                    // certified unique argmin: exact resolve (all lanes)
                    jstar = j1;
                    double vj = vvl[jstar];
                    float p1 = pn1l[jstar], p0 = 0.0f;
                    if (anyCh0) {
                        float2 sc = ((const float2*)ps)[jstar];
                        float mx = fmaxf(sc.x, sc.y);
                        float e0 = expf(sc.x - mx), e1 = expf(sc.y - mx);
                        p0 = -(e0 / (e0 + e1));
                    }
                    float2 qp = qxl[jstar];
                    double bb = INFD; int pr = -1;
                    for (int s = 0; s < Srow; ++s) {
                        float pres = rec_ch1[s] ? p1 : p0;
                        float cfr = pres + (fabsf(qp.x - rec_t0[s]) + fabsf(qp.y - rec_t1[s]));
                        double r = ((rec_minv[s] + (double)cfr) - rec_u[s]) - vj;
                        if (r < bb) { bb = r; pr = (int)rec_row[s]; }
                    }
                    sv = bb; pred = pr;
                } else {
                    // ambiguous/tied: exact resolve of all contenders
                    float thr = m1 + 2.0f * Dmax;
                    double bv = INFD; int bj = Nn, bp = -1;
                    #pragma unroll
                    for (int k = 0; k < 64; ++k) {
                        if (!((popped >> k) & 1ull) && shrF[k] <= thr) {
                            int j = (k << 6) | lane;
                            double vj = vvl[j];
                            float p1 = pn1l[j], p0 = 0.0f;
                            if (anyCh0) {
                                float2 sc = ((const float2*)ps)[j];
                                float mx = fmaxf(sc.x, sc.y);
                                float e0 = expf(sc.x - mx), e1 = expf(sc.y - mx);
                                p0 = -(e0 / (e0 + e1));
                            }
                            float2 qp = qxl[j];
                            double vv2 = INFD; int pr2 = -1;
                            for (int s = 0; s < Srow; ++s) {
                                float pres = rec_ch1[s] ? p1 : p0;
                                float cfr = pres + (fabsf(qp.x - rec_t0[s]) + fabsf(qp.y - rec_t1[s]));
                                double r = ((rec_minv[s] + (double)cfr) - rec_u[s]) - vj;
                                if (r < vv2) { vv2 = r; pr2 = (int)rec_row[s]; }
                            }
                            if (vv2 < bv || (vv2 == bv && j < bj)) { bv = vv2; bj = j; bp = pr2; }
                        }
                    }
                    #pragma unroll
                    for (int off = 32; off > 0; off >>= 1) {
                        double ov = __shfl_xor(bv, off);
                        int    oj = __shfl_xor(bj, off);
                        int    op = __shfl_xor(bp, off);
                        if (ov < bv || (ov == bv && oj < bj)) { bv = ov; bj = oj; bp = op; }
                    }
                    jstar = bj; sv = bv; pred = bp;
                }
                minv = sv;
                if (lane == 0) {
                    path_lds[jstar] = (unsigned char)pred;
                    pcol[Spop] = (short)jstar; pval[Spop] = sv; pvold[Spop] = vvl[jstar];
                    vvl[jstar] = -INFD;
                }
                if (lane == (jstar & 63)) popped |= (1ull << (jstar >> 6));
                Spop++;
                int r4 = (int)row4col_s[jstar];
                if (r4 < 0) { sink = jstar; break; }
                ri = r4; ur = uu[r4]; rt0 = tx0[r4]; rt1 = tx1[r4];
                rch1 = tch1[r4] != 0;
                anyCh0 = anyCh0 || !rch1;
                Umax = fmaxf(Umax, fabsf((float)ur));
                if (lane == 0) {
                    rec_minv[Srow] = sv; rec_u[Srow] = ur;
                    rec_t0[Srow] = rt0; rec_t1[Srow] = rt1;
                    rec_row[Srow] = (short)r4; rec_cc[Srow] = 0;
                    rec_ch1[Srow] = rch1 ? 1 : 0;
                }
                Srow++;
            }
        }

        // ============ row end: exact duals + augment ============
        const double mF = minv;
        for (int s = lane; s < Srow; s += 64) {
            int r = (int)rec_row[s];
            if (s == 0) uu[r] += mF;
            else        uu[r] += mF - rec_minv[s];
        }
        for (int e = lane; e < Spop; e += 64) {
            int c = (int)pcol[e];
            vvl[c] = pvold[e] - (mF - pval[e]);   // sink: -0 => exact restore
        }
        Vcap += (float)(mF - pval[0]) + 1e-6f;    // pops nondecreasing
        if (lane == 0) {
            int j = sink;
            for (;;) {
                int i2 = (int)path_lds[j];
                row4col_s[j] = (signed char)i2;
                int nxt = (int)col4row[i2];
                col4row[i2] = (short)j;
                j = nxt;
                if (i2 == cur_row) break;
            }
        }
    }

    // ---------------- emit ----------------
    for (int r = lane; r < Mm; r += 64) {
        int myj = (int)col4row[r];
        int rank = 0;
        for (int t = 0; t < Mm; ++t) rank += ((int)col4row[t] < myj) ? 1 : 0;
        out[b * Mm + r] = b;                      // batch_idx
        out[Bb * Mm + b * Mm + rank] = myj;       // src_idx (sorted)
        out[2 * Bb * Mm + b * Mm + rank] = r;     // tgt_idx
    }
}

extern "C" void kernel_launch(void* const* d_in, const int* in_sizes, int n_in,
                              void* d_out, int out_size, void* d_ws, size_t ws_size,
                              hipStream_t stream) {
    (void)in_sizes; (void)n_in; (void)d_ws; (void)ws_size; (void)out_size;
    const float* predict_scores = (const float*)d_in[0];
    const float* predict_points = (const float*)d_in[1];
    const int*   scores         = (const int*)d_in[2];
    const float* points         = (const float*)d_in[3];
    int* out = (int*)d_out;
    hipLaunchKernelGGL(hungarian_kernel, dim3(Bb), dim3(512), 0, stream,
                       predict_scores, predict_points, scores, points, out);
}

// Round 9
// 655.035 us; speedup vs baseline: 2.9904x; 1.0223x over previous
//
#include <hip/hip_runtime.h>

// Batched Hungarian matcher — TRAJECTORY-EXACT Jonker-Volgenant replication
// of the numpy reference (zero initial duals, rows in order, exact f64 on
// exact f32 costs, lowest-index tie-breaks).
//
// R9: SPECULATIVE PAIRWISE SEARCH OVERLAP. JV searches mutate duals /
// matching only at row end, so the searches for rows (r, r+1) both run
// against the post-(r-1) snapshot concurrently: group 0 (waves 0-3) solves
// row r, group 1 (waves 4-7) speculatively solves row r+1, lockstep through
// the same workgroup barriers with private shortest/path/record state.
// Commit r; accept r+1 iff popped(r+1) is disjoint from popped(r) (incl.
// sink_r). Disjointness + monotone rounding (v only decreases on popped(r),
// so true reduced costs there only grow) => r+1's speculative pops, values,
// predecessors and dual updates are bit-identical to the sequential run.
// On conflict, slide the window: rerun r+1 as the committed search while
// speculating r+2. Scan is the proven exact-f64 full scan (R2 core) — no
// certification machinery, no spill-prone 64-entry register arrays.

#define Bb 32
#define Nn 4096
#define Mm 128
#define GT 256         // threads per search group
#define KG 16          // columns per thread (Nn / GT)
#define RECMAX 140

__global__ __launch_bounds__(512, 2)
void hungarian_kernel(const float* __restrict__ predict_scores,
                      const float* __restrict__ predict_points,
                      const int*   __restrict__ scores,
                      const float* __restrict__ points,
                      int* __restrict__ out)
{
    __shared__ double vvl[Nn];              // column duals (exact f64)
    __shared__ unsigned char path2[2][Nn];  // per-group predecessor rows
    __shared__ short  row4col[Nn];          // matched row per col (-1 free)
    __shared__ double uu[Mm];               // row duals
    __shared__ short  col4row[Mm];
    __shared__ double srow_val2[2][Mm];     // minv when row scanned (per group)
    __shared__ unsigned char SRr2[2][Mm];   // scanned-row flags (per group)
    __shared__ float  tx0[Mm], tx1[Mm];
    __shared__ int    tch[Mm];
    __shared__ short  scol2[2][RECMAX];     // popped matched cols (per group)
    __shared__ double sval2[2][RECMAX];     // their exact pop values
    __shared__ double wmin2[2][4];          // per-group 4-wave reduce slots
    __shared__ int    wjmin2[2][4];
    __shared__ int    doneF[2], sink2[2], Spop2[2], conflict;
    __shared__ double minvF2[2];
    __shared__ unsigned int bmapA[Nn / 32]; // bitmap of A's popped cols

    const int tid = threadIdx.x;
    const int b   = blockIdx.x;
    const int g   = tid >> 8;      // search group 0 / 1
    const int gl  = tid & 255;     // lane within group
    const double INFD = __builtin_inf();

    // ---------------- setup ----------------
    const float* ps = predict_scores + (size_t)b * Nn * 2;
    const float* pp = predict_points + (size_t)b * Nn * 2;
    float negp0[KG], negp1[KG], qx0[KG], qx1[KG];
    #pragma unroll
    for (int k = 0; k < KG; ++k) {          // both groups load identically
        int j = gl + (k << 8);
        float2 sc = ((const float2*)ps)[j];
        float mx = fmaxf(sc.x, sc.y);
        float e0 = expf(sc.x - mx), e1 = expf(sc.y - mx);
        float sm = e0 + e1;
        negp0[k] = -(e0 / sm);
        negp1[k] = -(e1 / sm);
        float2 qp = ((const float2*)pp)[j];
        qx0[k] = qp.x; qx1[k] = qp.y;
    }
    for (int j = tid; j < Nn; j += 512) { vvl[j] = 0.0; row4col[j] = -1; }
    if (tid < Mm) {
        uu[tid] = 0.0; col4row[tid] = -1;
        tx0[tid] = points[(size_t)b * Mm * 2 + 2 * tid];
        tx1[tid] = points[(size_t)b * Mm * 2 + 2 * tid + 1];
        tch[tid] = scores[(size_t)b * Mm + tid];
    }
    __syncthreads();

    // ---------------- sliding-window pair solve ----------------
    int nxt = 0;
    while (nxt < Mm) {
        const int ra = nxt;
        const int rb = (nxt + 1 < Mm) ? nxt + 1 : -1;
        const int myrow = (g == 0) ? ra : rb;
        const bool act = (myrow >= 0);

        double shr[KG];
        #pragma unroll
        for (int k = 0; k < KG; ++k) shr[k] = INFD;
        unsigned scm = 0;                  // scanned-column bits (this thread)
        int    i = myrow, Spop = 0, sink = -1;
        double minv = 0.0;
        if (act) for (int r = gl; r < Mm; r += GT) SRr2[g][r] = 0;
        if (gl == 0) doneF[g] = act ? 0 : 1;
        __syncthreads();

        // ---- lockstep concurrent searches ----
        for (;;) {
            if (doneF[0] && doneF[1]) break;      // uniform (read post-barrier)
            if (act && sink < 0) {
                const double ui = uu[i];
                const float  t0 = tx0[i], t1 = tx1[i];
                const int    ch = tch[i];
                double bv = INFD; int bj = Nn;
                #pragma unroll
                for (int k = 0; k < KG; ++k) {
                    int j = gl + (k << 8);
                    float cf = ((ch == 1) ? negp1[k] : negp0[k])
                             + (fabsf(qx0[k] - t0) + fabsf(qx1[k] - t1));
                    double r = ((minv + (double)cf) - ui) - vvl[j]; // numpy order
                    bool sc = (scm >> k) & 1u;
                    if (!sc && r < shr[k]) { shr[k] = r; path2[g][j] = (unsigned char)i; }
                    double sj = sc ? INFD : shr[k];
                    if (sj < bv) { bv = sj; bj = j; }  // k asc => lowest j on tie
                }
                #pragma unroll
                for (int off = 32; off > 0; off >>= 1) {
                    double ov = __shfl_xor(bv, off);
                    int    oj = __shfl_xor(bj, off);
                    if (ov < bv || (ov == bv && oj < bj)) { bv = ov; bj = oj; }
                }
                if ((gl & 63) == 0) { wmin2[g][gl >> 6] = bv; wjmin2[g][gl >> 6] = bj; }
            }
            __syncthreads();                       // B1: publish slots
            if (act && sink < 0) {
                double best = wmin2[g][0]; int bestj = wjmin2[g][0];
                #pragma unroll
                for (int w = 1; w < 4; ++w) {
                    double ov = wmin2[g][w]; int oj = wjmin2[g][w];
                    if (ov < best || (ov == best && oj < bestj)) { best = ov; bestj = oj; }
                }
                minv = best;
                if ((bestj & 255) == gl) scm |= 1u << (bestj >> 8);
                int r4 = row4col[bestj];           // pre-pair snapshot (commits deferred)
                if (r4 < 0) {
                    sink = bestj;
                    if (gl == 0) { doneF[g] = 1; minvF2[g] = best;
                                   sink2[g] = bestj; Spop2[g] = Spop; }
                } else {
                    if (gl == 0) {
                        SRr2[g][r4] = 1; srow_val2[g][r4] = best;
                        scol2[g][Spop] = (short)bestj; sval2[g][Spop] = best;
                    }
                    Spop++; i = r4;
                }
            }
            __syncthreads();                       // B2: publish done/records
        }

        // ---- commit A (row ra, group-0 results) + build bitmap ----
        const double mA = minvF2[0];
        const int SA = Spop2[0];
        for (int r = tid; r < Mm; r += 512) {
            if (r == ra) uu[r] += mA;
            else if (SRr2[0][r]) uu[r] += mA - srow_val2[0][r];
        }
        for (int e = tid; e < SA; e += 512) {
            int c = scol2[0][e];
            vvl[c] -= (mA - sval2[0][e]);          // sink excluded: -0, no-op
        }
        for (int w = tid; w < Nn / 32; w += 512) bmapA[w] = 0;
        if (tid == 0) conflict = 0;
        __syncthreads();
        for (int e = tid; e < SA; e += 512) {
            int c = scol2[0][e];
            atomicOr(&bmapA[c >> 5], 1u << (c & 31));
        }
        if (tid == 0) {
            int sA = sink2[0];
            atomicOr(&bmapA[sA >> 5], 1u << (sA & 31));
            int j = sA;                             // augment A
            for (;;) {
                int i2 = (int)path2[0][j];
                row4col[j] = (short)i2;
                int nx2 = col4row[i2];
                col4row[i2] = (short)j;
                j = nx2;
                if (i2 == ra) break;
            }
        }
        __syncthreads();
        // ---- certificate: popped(B) disjoint from popped(A) U {sink_A} ----
        if (rb >= 0) {
            int SB = Spop2[1];
            for (int e = tid; e < SB; e += 512) {
                int c = scol2[1][e];
                if ((bmapA[c >> 5] >> (c & 31)) & 1u) conflict = 1;
            }
            if (tid == 0) {
                int c = sink2[1];
                if ((bmapA[c >> 5] >> (c & 31)) & 1u) conflict = 1;
            }
        }
        __syncthreads();
        const bool okB = (rb >= 0) && (conflict == 0);
        if (okB) {                                  // commit B (bit-exact)
            const double mB = minvF2[1];
            const int SB = Spop2[1];
            for (int r = tid; r < Mm; r += 512) {
                if (r == rb) uu[r] += mB;
                else if (SRr2[1][r]) uu[r] += mB - srow_val2[1][r];
            }
            for (int e = tid; e < SB; e += 512) {
                int c = scol2[1][e];
                vvl[c] -= (mB - sval2[1][e]);
            }
            if (tid == 0) {
                int j = sink2[1];                   // augment B (disjoint path)
                for (;;) {
                    int i2 = (int)path2[1][j];
                    row4col[j] = (short)i2;
                    int nx2 = col4row[i2];
                    col4row[i2] = (short)j;
                    j = nx2;
                    if (i2 == rb) break;
                }
            }
        }
        __syncthreads();
        nxt += okB ? 2 : 1;     // conflict => rb reruns as next committed search
    }

    // ---------------- emit (batch, src sorted ascending, tgt) ----------------
    if (tid < Mm) {
        int myj = (int)col4row[tid];
        int rank = 0;
        #pragma unroll 4
        for (int t = 0; t < Mm; ++t) rank += ((int)col4row[t] < myj) ? 1 : 0;
        out[b * Mm + tid] = b;                      // batch_idx
        out[Bb * Mm + b * Mm + rank] = myj;         // src_idx (sorted)
        out[2 * Bb * Mm + b * Mm + rank] = tid;     // tgt_idx
    }
}

extern "C" void kernel_launch(void* const* d_in, const int* in_sizes, int n_in,
                              void* d_out, int out_size, void* d_ws, size_t ws_size,
                              hipStream_t stream) {
    (void)in_sizes; (void)n_in; (void)d_ws; (void)ws_size; (void)out_size;
    const float* predict_scores = (const float*)d_in[0];
    const float* predict_points = (const float*)d_in[1];
    const int*   scores         = (const int*)d_in[2];
    const float* points         = (const float*)d_in[3];
    int* out = (int*)d_out;
    hipLaunchKernelGGL(hungarian_kernel, dim3(Bb), dim3(512), 0, stream,
                       predict_scores, predict_points, scores, points, out);
}